// Round 2
// baseline (28.651 us; speedup 1.0000x reference)
//
#include <hip/hip_runtime.h>

#define BB     128
#define CCH    2048
#define NRODT  512
#define NEST   128
#define NF     100
#define NHID   128
#define BT     32      // batch rows per forest block
#define TPB2   512     // threads per block, kernel 2

__device__ __forceinline__ void fma4(float4& a, const float4& x, float p) {
    a.x = fmaf(x.x, p, a.x);
    a.y = fmaf(x.y, p, a.y);
    a.z = fmaf(x.z, p, a.z);
    a.w = fmaf(x.w, p, a.w);
}

__device__ __forceinline__ float4 scale4(const float4& a, float s) {
    return make_float4(a.x * s, a.y * s, a.z * s, a.w * s);
}

// ---------------------------------------------------------------------------
// Kernel 1: per-(b,g) phi_2 pipeline: GN -> 4x4 matmul -> ReLU -> GN -> 4->1
// One thread per (b,g). Writes w[b*512+g] to workspace.
// ---------------------------------------------------------------------------
__global__ __launch_bounds__(256) void phi2_kernel(
    const float* __restrict__ O,
    const float* __restrict__ g1w, const float* __restrict__ g1b,
    const float* __restrict__ W1,  const float* __restrict__ b1,
    const float* __restrict__ g2w, const float* __restrict__ g2b,
    const float* __restrict__ W2,  const float* __restrict__ b2,
    float* __restrict__ wbuf)
{
    const int t = blockIdx.x * 256 + threadIdx.x;   // 0 .. B*NRODT-1
    const int b = t >> 9;
    const int g = t & (NRODT - 1);

    const float4 x = *reinterpret_cast<const float4*>(O + (size_t)b * CCH + g * 4);

    // GroupNorm 1 (biased var over 4 elems)
    float m  = 0.25f * ((x.x + x.y) + (x.z + x.w));
    float d0 = x.x - m, d1 = x.y - m, d2 = x.z - m, d3 = x.w - m;
    float v  = 0.25f * ((d0 * d0 + d1 * d1) + (d2 * d2 + d3 * d3));
    float iv = rsqrtf(v + 1e-5f);
    const float4 gw1 = *reinterpret_cast<const float4*>(g1w + g * 4);
    const float4 gb1 = *reinterpret_cast<const float4*>(g1b + g * 4);
    float a0 = fmaf(d0 * iv, gw1.x, gb1.x);
    float a1 = fmaf(d1 * iv, gw1.y, gb1.y);
    float a2 = fmaf(d2 * iv, gw1.z, gb1.z);
    float a3 = fmaf(d3 * iv, gw1.w, gb1.w);

    // grouped conv1: y_e = b1[g,e] + sum_d a_d * W1[g,d,e]
    const float4 r0 = *reinterpret_cast<const float4*>(W1 + g * 16 + 0);
    const float4 r1 = *reinterpret_cast<const float4*>(W1 + g * 16 + 4);
    const float4 r2 = *reinterpret_cast<const float4*>(W1 + g * 16 + 8);
    const float4 r3 = *reinterpret_cast<const float4*>(W1 + g * 16 + 12);
    const float4 bc = *reinterpret_cast<const float4*>(b1 + g * 4);
    float y0 = fmaf(a0, r0.x, fmaf(a1, r1.x, fmaf(a2, r2.x, fmaf(a3, r3.x, bc.x))));
    float y1 = fmaf(a0, r0.y, fmaf(a1, r1.y, fmaf(a2, r2.y, fmaf(a3, r3.y, bc.y))));
    float y2 = fmaf(a0, r0.z, fmaf(a1, r1.z, fmaf(a2, r2.z, fmaf(a3, r3.z, bc.z))));
    float y3 = fmaf(a0, r0.w, fmaf(a1, r1.w, fmaf(a2, r2.w, fmaf(a3, r3.w, bc.w))));
    y0 = fmaxf(y0, 0.f); y1 = fmaxf(y1, 0.f); y2 = fmaxf(y2, 0.f); y3 = fmaxf(y3, 0.f);

    // GroupNorm 2
    m  = 0.25f * ((y0 + y1) + (y2 + y3));
    d0 = y0 - m; d1 = y1 - m; d2 = y2 - m; d3 = y3 - m;
    v  = 0.25f * ((d0 * d0 + d1 * d1) + (d2 * d2 + d3 * d3));
    iv = rsqrtf(v + 1e-5f);
    const float4 gw2 = *reinterpret_cast<const float4*>(g2w + g * 4);
    const float4 gb2 = *reinterpret_cast<const float4*>(g2b + g * 4);
    float z0 = fmaf(d0 * iv, gw2.x, gb2.x);
    float z1 = fmaf(d1 * iv, gw2.y, gb2.y);
    float z2 = fmaf(d2 * iv, gw2.z, gb2.z);
    float z3 = fmaf(d3 * iv, gw2.w, gb2.w);

    // grouped conv2 (NHEAD=1): w = b2[g] + sum_d z_d * W2[g,d,0]
    const float4 w2 = *reinterpret_cast<const float4*>(W2 + g * 4);
    float res = fmaf(z0, w2.x, fmaf(z1, w2.y, fmaf(z2, w2.z, fmaf(z3, w2.w, b2[g]))));

    wbuf[t] = res;   // [B, NRODT], t = b*512 + g  -> coalesced
}

// ---------------------------------------------------------------------------
// Kernel 2: per (f, 32-batch tile): gather w via swr, softmax over 128
// estimators (denominator factored out), weighted sum of E rows.
// 512 threads (8 waves); thread owns 4 h (float4) x 2 batch rows.
// p-values stored TRANSPOSED in LDS -> one ds_read_b64 per iteration.
// ---------------------------------------------------------------------------
__global__ __launch_bounds__(TPB2) void forest_kernel(
    const float* __restrict__ wv,   // [B, NRODT]
    const float* __restrict__ E,    // [NRODT, NHID]
    const int*   __restrict__ swr,  // [NF, NEST]
    float* __restrict__ out)        // [B, NF, NHID]
{
    __shared__ int   ids[NEST];
    __shared__ float sh_t[NEST][BT + 4];  // transposed, stride 36 floats (144B, 16B-aligned)
    __shared__ float invs[BT];

    const int f   = blockIdx.x;
    const int b0  = blockIdx.y * BT;
    const int tid = threadIdx.x;

    if (tid < NEST) ids[tid] = swr[f * NEST + tid];
    __syncthreads();

    // ---- softmax numerators: 16 threads per batch row ----
    {
        const int bl = tid >> 4;          // 0..31
        const int j  = tid & 15;
        const float* wrow = wv + (size_t)(b0 + bl) * NRODT;
        float val[8];
        float mx = -3.4e38f;
        #pragma unroll
        for (int k = 0; k < 8; ++k) {
            val[k] = wrow[ids[j + (k << 4)]];
            mx = fmaxf(mx, val[k]);
        }
        mx = fmaxf(mx, __shfl_xor(mx, 1));
        mx = fmaxf(mx, __shfl_xor(mx, 2));
        mx = fmaxf(mx, __shfl_xor(mx, 4));
        mx = fmaxf(mx, __shfl_xor(mx, 8));
        float sum = 0.f;
        #pragma unroll
        for (int k = 0; k < 8; ++k) {
            float ex = __expf(val[k] - mx);
            sum += ex;
            sh_t[j + (k << 4)][bl] = ex;   // bank = (4e+bl)%32: worst 2-way = free
        }
        sum += __shfl_xor(sum, 1);
        sum += __shfl_xor(sum, 2);
        sum += __shfl_xor(sum, 4);
        sum += __shfl_xor(sum, 8);
        if (j == 0) invs[bl] = 1.f / sum;
    }
    __syncthreads();

    // ---- weighted combine: out[b, f, h] = (sum_e p_e * E[ids[e], h]) * inv ----
    const int hcol = tid & 31;     // 32 float4 columns cover NHID=128
    const int rg   = tid >> 5;     // 0..15 row groups, 2 batch rows each
    const int h0   = hcol << 2;
    const int r0   = rg << 1;

    const float* Eh   = E + h0;
    const int*   swrf = swr + f * NEST;   // wave-uniform -> scalar loads

    float4 acc0 = make_float4(0.f, 0.f, 0.f, 0.f);
    float4 acc1 = acc0;

    #pragma unroll 8
    for (int e = 0; e < NEST; ++e) {
        const int idx = swrf[e];                                   // s_load
        const float4 Ev = *reinterpret_cast<const float4*>(Eh + (size_t)idx * NHID);
        const float2 p  = *reinterpret_cast<const float2*>(&sh_t[e][r0]);  // ds_read_b64 broadcast
        fma4(acc0, Ev, p.x);
        fma4(acc1, Ev, p.y);
    }

    const float i0 = invs[r0 + 0], i1 = invs[r0 + 1];
    const size_t stride = (size_t)NF * NHID;
    float* op = out + (size_t)(b0 + r0) * stride + (size_t)f * NHID + h0;
    *reinterpret_cast<float4*>(op + 0 * stride) = scale4(acc0, i0);
    *reinterpret_cast<float4*>(op + 1 * stride) = scale4(acc1, i1);
}

// ---------------------------------------------------------------------------
extern "C" void kernel_launch(void* const* d_in, const int* in_sizes, int n_in,
                              void* d_out, int out_size, void* d_ws, size_t ws_size,
                              hipStream_t stream) {
    const float* O   = (const float*)d_in[0];
    const float* g1w = (const float*)d_in[1];
    const float* g1b = (const float*)d_in[2];
    const float* W1  = (const float*)d_in[3];
    const float* b1  = (const float*)d_in[4];
    const float* g2w = (const float*)d_in[5];
    const float* g2b = (const float*)d_in[6];
    const float* W2  = (const float*)d_in[7];
    const float* b2  = (const float*)d_in[8];
    const float* E   = (const float*)d_in[9];
    const int*   swr = (const int*)d_in[10];

    float* wbuf = (float*)d_ws;          // [B, NRODT] = 256 KB
    float* out  = (float*)d_out;         // [B, NF, NHID]

    phi2_kernel<<<dim3((BB * NRODT) / 256), 256, 0, stream>>>(
        O, g1w, g1b, W1, b1, g2w, g2b, W2, b2, wbuf);

    forest_kernel<<<dim3(NF, BB / BT), TPB2, 0, stream>>>(wbuf, E, swr, out);
}

// Round 3
// 24.063 us; speedup vs baseline: 1.1907x; 1.1907x over previous
//
#include <hip/hip_runtime.h>

#define BB     128
#define CCH    2048
#define NRODT  512
#define NEST   128
#define NF     100
#define NHID   128
#define BT     32      // batch rows per forest block
#define TPB2   512     // threads per block, kernel 2

__device__ __forceinline__ void fma4(float4& a, const float4& x, float p) {
    a.x = fmaf(x.x, p, a.x);
    a.y = fmaf(x.y, p, a.y);
    a.z = fmaf(x.z, p, a.z);
    a.w = fmaf(x.w, p, a.w);
}

// ---------------------------------------------------------------------------
// Kernel 1: per-(b,g) phi_2 pipeline: GN -> 4x4 matmul -> ReLU -> GN -> 4->1
// One thread per (b,g). Writes w[b*512+g] to workspace.
// ---------------------------------------------------------------------------
__global__ __launch_bounds__(256) void phi2_kernel(
    const float* __restrict__ O,
    const float* __restrict__ g1w, const float* __restrict__ g1b,
    const float* __restrict__ W1,  const float* __restrict__ b1,
    const float* __restrict__ g2w, const float* __restrict__ g2b,
    const float* __restrict__ W2,  const float* __restrict__ b2,
    float* __restrict__ wbuf)
{
    const int t = blockIdx.x * 256 + threadIdx.x;   // 0 .. B*NRODT-1
    const int b = t >> 9;
    const int g = t & (NRODT - 1);

    const float4 x = *reinterpret_cast<const float4*>(O + (size_t)b * CCH + g * 4);

    // GroupNorm 1 (biased var over 4 elems)
    float m  = 0.25f * ((x.x + x.y) + (x.z + x.w));
    float d0 = x.x - m, d1 = x.y - m, d2 = x.z - m, d3 = x.w - m;
    float v  = 0.25f * ((d0 * d0 + d1 * d1) + (d2 * d2 + d3 * d3));
    float iv = rsqrtf(v + 1e-5f);
    const float4 gw1 = *reinterpret_cast<const float4*>(g1w + g * 4);
    const float4 gb1 = *reinterpret_cast<const float4*>(g1b + g * 4);
    float a0 = fmaf(d0 * iv, gw1.x, gb1.x);
    float a1 = fmaf(d1 * iv, gw1.y, gb1.y);
    float a2 = fmaf(d2 * iv, gw1.z, gb1.z);
    float a3 = fmaf(d3 * iv, gw1.w, gb1.w);

    // grouped conv1: y_e = b1[g,e] + sum_d a_d * W1[g,d,e]
    const float4 r0 = *reinterpret_cast<const float4*>(W1 + g * 16 + 0);
    const float4 r1 = *reinterpret_cast<const float4*>(W1 + g * 16 + 4);
    const float4 r2 = *reinterpret_cast<const float4*>(W1 + g * 16 + 8);
    const float4 r3 = *reinterpret_cast<const float4*>(W1 + g * 16 + 12);
    const float4 bc = *reinterpret_cast<const float4*>(b1 + g * 4);
    float y0 = fmaf(a0, r0.x, fmaf(a1, r1.x, fmaf(a2, r2.x, fmaf(a3, r3.x, bc.x))));
    float y1 = fmaf(a0, r0.y, fmaf(a1, r1.y, fmaf(a2, r2.y, fmaf(a3, r3.y, bc.y))));
    float y2 = fmaf(a0, r0.z, fmaf(a1, r1.z, fmaf(a2, r2.z, fmaf(a3, r3.z, bc.z))));
    float y3 = fmaf(a0, r0.w, fmaf(a1, r1.w, fmaf(a2, r2.w, fmaf(a3, r3.w, bc.w))));
    y0 = fmaxf(y0, 0.f); y1 = fmaxf(y1, 0.f); y2 = fmaxf(y2, 0.f); y3 = fmaxf(y3, 0.f);

    // GroupNorm 2
    m  = 0.25f * ((y0 + y1) + (y2 + y3));
    d0 = y0 - m; d1 = y1 - m; d2 = y2 - m; d3 = y3 - m;
    v  = 0.25f * ((d0 * d0 + d1 * d1) + (d2 * d2 + d3 * d3));
    iv = rsqrtf(v + 1e-5f);
    const float4 gw2 = *reinterpret_cast<const float4*>(g2w + g * 4);
    const float4 gb2 = *reinterpret_cast<const float4*>(g2b + g * 4);
    float z0 = fmaf(d0 * iv, gw2.x, gb2.x);
    float z1 = fmaf(d1 * iv, gw2.y, gb2.y);
    float z2 = fmaf(d2 * iv, gw2.z, gb2.z);
    float z3 = fmaf(d3 * iv, gw2.w, gb2.w);

    // grouped conv2 (NHEAD=1): w = b2[g] + sum_d z_d * W2[g,d,0]
    const float4 w2 = *reinterpret_cast<const float4*>(W2 + g * 4);
    float res = fmaf(z0, w2.x, fmaf(z1, w2.y, fmaf(z2, w2.z, fmaf(z3, w2.w, b2[g]))));

    wbuf[t] = res;   // [B, NRODT], t = b*512 + g  -> coalesced
}

// ---------------------------------------------------------------------------
// Kernel 2: per (f, 32-batch tile). 512 threads = 4 e-slices x (4 rowgroups
// x 32 hcols). Each thread: 8 batch rows x 1 float4 col over 32 estimators
// -> 32 FMAs per E-load (halves E traffic vs R1). Two-stage LDS reduction
// combines the 4 e-slices.
// ---------------------------------------------------------------------------
__global__ __launch_bounds__(TPB2) void forest_kernel(
    const float* __restrict__ wv,   // [B, NRODT]
    const float* __restrict__ E,    // [NRODT, NHID]
    const int*   __restrict__ swr,  // [NF, NEST]
    float* __restrict__ out)        // [B, NF, NHID]
{
    __shared__ int   ids[NEST];
    __shared__ float sh_t[NEST][BT + 4];  // transposed p, stride 36 floats
    __shared__ float invs[BT];
    __shared__ float red[256][36];        // reduction buffer, 16B-aligned rows

    const int f   = blockIdx.x;
    const int b0  = blockIdx.y * BT;
    const int tid = threadIdx.x;

    if (tid < NEST) ids[tid] = swr[f * NEST + tid];
    __syncthreads();

    // ---- softmax numerators: 16 threads per batch row ----
    {
        const int bl = tid >> 4;          // 0..31
        const int j  = tid & 15;
        const float* wrow = wv + (size_t)(b0 + bl) * NRODT;
        float val[8];
        float mx = -3.4e38f;
        #pragma unroll
        for (int k = 0; k < 8; ++k) {
            val[k] = wrow[ids[j + (k << 4)]];
            mx = fmaxf(mx, val[k]);
        }
        mx = fmaxf(mx, __shfl_xor(mx, 1));
        mx = fmaxf(mx, __shfl_xor(mx, 2));
        mx = fmaxf(mx, __shfl_xor(mx, 4));
        mx = fmaxf(mx, __shfl_xor(mx, 8));
        float sum = 0.f;
        #pragma unroll
        for (int k = 0; k < 8; ++k) {
            float ex = __expf(val[k] - mx);
            sum += ex;
            sh_t[j + (k << 4)][bl] = ex;
        }
        sum += __shfl_xor(sum, 1);
        sum += __shfl_xor(sum, 2);
        sum += __shfl_xor(sum, 4);
        sum += __shfl_xor(sum, 8);
        if (j == 0) invs[bl] = 1.f / sum;
    }
    __syncthreads();

    // ---- weighted combine over a 32-estimator slice ----
    const int eq   = tid >> 7;          // 0..3  e-slice (wave-uniform)
    const int rg   = (tid >> 5) & 3;    // 0..3  rowgroup
    const int hcol = tid & 31;          // float4 column
    const int h0   = hcol << 2;
    const int r0   = rg << 3;           // 8 rows per thread

    const float* Eh   = E + h0;
    const int*   swrf = swr + f * NEST; // wave-uniform indices -> scalar loads

    float4 acc[8];
    #pragma unroll
    for (int i = 0; i < 8; ++i) acc[i] = make_float4(0.f, 0.f, 0.f, 0.f);

    const int ebase = eq << 5;
    #pragma unroll 8
    for (int k = 0; k < 32; ++k) {
        const int e   = ebase + k;
        const int idx = swrf[e];
        const float4 Ev = *reinterpret_cast<const float4*>(Eh + (size_t)idx * NHID);
        const float4 pa = *reinterpret_cast<const float4*>(&sh_t[e][r0]);
        const float4 pb = *reinterpret_cast<const float4*>(&sh_t[e][r0 + 4]);
        fma4(acc[0], Ev, pa.x);
        fma4(acc[1], Ev, pa.y);
        fma4(acc[2], Ev, pa.z);
        fma4(acc[3], Ev, pa.w);
        fma4(acc[4], Ev, pb.x);
        fma4(acc[5], Ev, pb.y);
        fma4(acc[6], Ev, pb.z);
        fma4(acc[7], Ev, pb.w);
    }

    // ---- two-stage reduction of the 4 e-slices ----
    const int slot = tid & 127;

    if (eq >= 2) {
        float* dst = &red[(eq - 2) * 128 + slot][0];
        #pragma unroll
        for (int i = 0; i < 8; ++i)
            *reinterpret_cast<float4*>(dst + i * 4) = acc[i];
    }
    __syncthreads();
    if (eq < 2) {
        const float* src = &red[eq * 128 + slot][0];
        #pragma unroll
        for (int i = 0; i < 8; ++i) {
            const float4 t = *reinterpret_cast<const float4*>(src + i * 4);
            acc[i].x += t.x; acc[i].y += t.y; acc[i].z += t.z; acc[i].w += t.w;
        }
    }
    __syncthreads();
    if (eq == 1) {
        float* dst = &red[slot][0];
        #pragma unroll
        for (int i = 0; i < 8; ++i)
            *reinterpret_cast<float4*>(dst + i * 4) = acc[i];
    }
    __syncthreads();
    if (eq == 0) {
        const float* src = &red[slot][0];
        const size_t stride = (size_t)NF * NHID;
        float* op = out + (size_t)(b0 + r0) * stride + (size_t)f * NHID + h0;
        #pragma unroll
        for (int i = 0; i < 8; ++i) {
            const float4 t = *reinterpret_cast<const float4*>(src + i * 4);
            const float s = invs[r0 + i];
            float4 r;
            r.x = (acc[i].x + t.x) * s;
            r.y = (acc[i].y + t.y) * s;
            r.z = (acc[i].z + t.z) * s;
            r.w = (acc[i].w + t.w) * s;
            *reinterpret_cast<float4*>(op + (size_t)i * stride) = r;
        }
    }
}

// ---------------------------------------------------------------------------
extern "C" void kernel_launch(void* const* d_in, const int* in_sizes, int n_in,
                              void* d_out, int out_size, void* d_ws, size_t ws_size,
                              hipStream_t stream) {
    const float* O   = (const float*)d_in[0];
    const float* g1w = (const float*)d_in[1];
    const float* g1b = (const float*)d_in[2];
    const float* W1  = (const float*)d_in[3];
    const float* b1  = (const float*)d_in[4];
    const float* g2w = (const float*)d_in[5];
    const float* g2b = (const float*)d_in[6];
    const float* W2  = (const float*)d_in[7];
    const float* b2  = (const float*)d_in[8];
    const float* E   = (const float*)d_in[9];
    const int*   swr = (const int*)d_in[10];

    float* wbuf = (float*)d_ws;          // [B, NRODT] = 256 KB
    float* out  = (float*)d_out;         // [B, NF, NHID]

    phi2_kernel<<<dim3((BB * NRODT) / 256), 256, 0, stream>>>(
        O, g1w, g1b, W1, b1, g2w, g2b, W2, b2, wbuf);

    forest_kernel<<<dim3(NF, BB / BT), TPB2, 0, stream>>>(wbuf, E, swr, out);
}